// Round 4
// baseline (489.876 us; speedup 1.0000x reference)
//
#include <hip/hip_runtime.h>
#include <stdint.h>

typedef unsigned short ushort_t;
typedef __attribute__((ext_vector_type(8))) short short8;
typedef __attribute__((ext_vector_type(4))) float floatx4;
typedef __attribute__((ext_vector_type(16))) float floatx16;

#define B_    32
#define C_    256
#define O_    256
#define HID_  65
#define HW_   4096
#define KDIM  2304          // C_ * 9
#define XP_H  66            // padded spatial edge
#define XPAD_ELEMS ((size_t)B_ * XP_H * XP_H * C_)   // 35,684,352 bf16
#define WAGG_ELEMS ((size_t)B_ * O_ * KDIM)          // 18,874,368 bf16

static __device__ __forceinline__ unsigned short f2bf(float f) {
  unsigned u = __float_as_uint(f);
  u += 0x7fffu + ((u >> 16) & 1u);        // RNE
  return (unsigned short)(u >> 16);
}

static __device__ __forceinline__ void gld_lds16(const void* g, void* l) {
  // async global->LDS, 16B/lane; LDS dest = wave-uniform base + lane*16
  __builtin_amdgcn_global_load_lds((__attribute__((address_space(1))) void*)(g),
                                   (__attribute__((address_space(3))) void*)(l),
                                   16, 0, 0);
}

// -------------------------------------------------------------- border ------
// zero only the pad borders of xpad; interior overwritten by pad_kernel.
__global__ void border_kernel(ushort_t* __restrict__ xpad) {
  const int b = blockIdx.x, p = blockIdx.y, t = threadIdx.x;
  uint4 z = {0u, 0u, 0u, 0u};
  uint4* base = (uint4*)(xpad + (size_t)b * XP_H * XP_H * C_);
  if (p == 0) {
    for (int i = t; i < 2112; i += 256) base[i] = z;
  } else if (p == 1) {
    for (int i = t; i < 2112; i += 256) base[(size_t)65 * 2112 + i] = z;
  } else if (p == 2) {
    for (int i = t; i < 64 * 32; i += 256) {
      const int h = 1 + (i >> 5), s = i & 31;
      base[(size_t)h * 2112 + s] = z;
    }
  } else {
    for (int i = t; i < 64 * 32; i += 256) {
      const int h = 1 + (i >> 5), s = i & 31;
      base[(size_t)h * 2112 + 65 * 32 + s] = z;
    }
  }
}

// ----------------------------------------------------------------- pad ------
// xpad[b][h+1][w+1][c] (bf16, HWC) from x[b][c][h][w] (fp32, CHW), PLUS
// pooling partials partial[hwT][b*C+c]. At BW floor (512 MB in + 71 MB out).
__global__ void pad_kernel(const float* __restrict__ x, ushort_t* __restrict__ xpad,
                           float* __restrict__ partial) {
  __shared__ float tile[64][65];                   // bank(c,hw) = (c+hw)%32
  const int hwT = blockIdx.x, cT = blockIdx.y, b = blockIdx.z;
  const int t = threadIdx.x;
  const int hw0 = hwT * 64, c0 = cT * 64;
  const float* src = x + ((size_t)(b * C_ + c0)) * HW_ + hw0;

  const int w4 = t & 15, cg = t >> 4;
#pragma unroll
  for (int i = 0; i < 4; ++i) {
    const int ci = cg + i * 16;
    const float4 v = *(const float4*)(src + (size_t)ci * HW_ + w4 * 4);
    tile[ci][w4 * 4 + 0] = v.x;
    tile[ci][w4 * 4 + 1] = v.y;
    tile[ci][w4 * 4 + 2] = v.z;
    tile[ci][w4 * 4 + 3] = v.w;
  }
  __syncthreads();

  if (t < 64) {
    float s = 0.f;
#pragma unroll
    for (int i = 0; i < 64; ++i) s += tile[t][i];
    partial[(size_t)hwT * (B_ * C_) + b * C_ + c0 + t] = s;
  }

  const int s8 = (t & 7) * 8, hb = t >> 3;
#pragma unroll
  for (int i = 0; i < 2; ++i) {
    const int hwi = hb + 32 * i;
    const int hw = hw0 + hwi;
    const int h = hw >> 6, w = hw & 63;
    ushort_t v[8];
#pragma unroll
    for (int j = 0; j < 8; ++j) v[j] = f2bf(tile[s8 + j][hwi]);
    *(uint4*)(xpad + (((size_t)b * XP_H + (h + 1)) * XP_H + (w + 1)) * C_ + c0 + s8) =
        *(const uint4*)v;
  }
}

// ---------------------------------------------------------------- attn ------
__global__ void attn_kernel(const float* __restrict__ partial,
                            const float* __restrict__ w1,
                            const float* __restrict__ w2,
                            const float* __restrict__ b2,
                            float* __restrict__ attn) {
  __shared__ float sp[C_];
  __shared__ float sh[HID_];
  const int b = blockIdx.x, t = threadIdx.x;
  {
    float s = 0.f;
#pragma unroll
    for (int i = 0; i < 64; ++i) s += partial[(size_t)i * (B_ * C_) + b * C_ + t];
    sp[t] = s * (1.f / 4096.f);
  }
  __syncthreads();
  if (t < HID_) {
    float a = 0.f;
    for (int c = 0; c < C_; ++c) a += sp[c] * w1[t * C_ + c];
    sh[t] = fmaxf(a, 0.f);
  }
  __syncthreads();
  float lg[4];
#pragma unroll
  for (int k = 0; k < 4; ++k) {
    float a = b2[k * O_ + t];
    for (int j = 0; j < HID_; ++j) a += sh[j] * w2[(k * O_ + t) * HID_ + j];
    lg[k] = a * 2.0f;                              // / TEMP (0.5)
  }
  float mx = fmaxf(fmaxf(lg[0], lg[1]), fmaxf(lg[2], lg[3]));
  float e0 = expf(lg[0] - mx), e1 = expf(lg[1] - mx);
  float e2 = expf(lg[2] - mx), e3 = expf(lg[3] - mx);
  float inv = 1.f / (e0 + e1 + e2 + e3);
  attn[(b * 4 + 0) * O_ + t] = e0 * inv;
  attn[(b * 4 + 1) * O_ + t] = e1 * inv;
  attn[(b * 4 + 2) * O_ + t] = e2 * inv;
  attn[(b * 4 + 3) * O_ + t] = e3 * inv;
}

// ----------------------------------------------------------------- agg ------
// wagg[b][o][ck], ck = tap*256 + c. grid (O_, 4 b-groups); thread t owns
// (tap = t>>5, c = (t&31)*8 .. +7) -> one uint4 store per b; group bi also
// covers tap 8 for b-sub bi.
__global__ void agg_kernel(const float* __restrict__ attn,
                           const float* __restrict__ wt,
                           ushort_t* __restrict__ wagg) {
  const int o = blockIdx.x, bg = blockIdx.y;
  const int t = threadIdx.x;
  const int n = t >> 5;                            // tap 0..7
  const int c8 = (t & 31) * 8;
  float wr[4][8], wr8[4][8];
#pragma unroll
  for (int k = 0; k < 4; ++k) {
    const float* base = wt + (size_t)(k * O_ + o) * KDIM + n;
    const float* base8 = wt + (size_t)(k * O_ + o) * KDIM + 8;
#pragma unroll
    for (int j = 0; j < 8; ++j) {
      wr[k][j]  = base[(size_t)(c8 + j) * 9];
      wr8[k][j] = base8[(size_t)(c8 + j) * 9];
    }
  }
#pragma unroll
  for (int bi = 0; bi < 8; ++bi) {
    const int b = bg * 8 + bi;
    const float a0 = attn[(b * 4 + 0) * O_ + o];
    const float a1 = attn[(b * 4 + 1) * O_ + o];
    const float a2 = attn[(b * 4 + 2) * O_ + o];
    const float a3 = attn[(b * 4 + 3) * O_ + o];
    ushort_t* dst = wagg + (size_t)(b * O_ + o) * KDIM;
    ushort_t v[8];
#pragma unroll
    for (int j = 0; j < 8; ++j)
      v[j] = f2bf(a0 * wr[0][j] + a1 * wr[1][j] + a2 * wr[2][j] + a3 * wr[3][j]);
    *(uint4*)(dst + n * C_ + c8) = *(const uint4*)v;
    if (n == bi) {
      ushort_t v8[8];
#pragma unroll
      for (int j = 0; j < 8; ++j)
        v8[j] = f2bf(a0 * wr8[0][j] + a1 * wr8[1][j] + a2 * wr8[2][j] + a3 * wr8[3][j]);
      *(uint4*)(dst + 8 * C_ + c8) = *(const uint4*)v8;
    }
  }
}

// ---------------------------------------------------------------- gemm ------
// 128x128 tile, BK=64, global_load_lds w=16, XOR slot swizzle.
// Round 4: (a) 32x32x16 MFMA (2382 vs 2075 TF ceiling; 128 vs 155 matrix-pipe
// cyc per wave-BK-step); (b) XCD-aware block swizzle: each XCD owns whole
// (b, both oT) groups -> per-XCD L2 working set 3.4 MB < 4 MB, wagg fetched
// once per XCD instead of 8x.
__global__ __launch_bounds__(256) void gemm_kernel(const ushort_t* __restrict__ xpad,
                                                   const ushort_t* __restrict__ wagg,
                                                   float* __restrict__ out) {
  __shared__ short lA[128 * 64];                   // 16 KB
  __shared__ short lB[128 * 64];                   // 16 KB

  // XCD swizzle: linear id -> XCD = id%8 (round-robin heuristic). Give XCD c
  // pairs p = c*8 .. c*8+7 where p = (b<<1)|oT; hwT = slot within pair.
  const int flat = blockIdx.x + 32 * (blockIdx.y + 2 * blockIdx.z);
  const int xcd = flat & 7;
  const int s   = flat >> 3;                       // 0..255
  const int p   = xcd * 8 + (s >> 5);              // 0..63
  const int hwT = s & 31;
  const int oT  = p & 1;
  const int b   = p >> 1;

  const int t    = threadIdx.x;
  const int lane = t & 63;
  const int wv   = t >> 6;

  const int hwBase = hwT << 7;
  const int h0     = hwT << 1;                     // 2 image rows per hw-tile
  const int oBase  = oT << 7;

  // staging: wave wv owns rows wv*32 + q*8 + (lane>>3); phys slot = lane&7,
  // logical k-chunk = phys ^ (row & 7).
  const int rS = lane >> 3;
  const int pS = lane & 7;
  size_t aG[4], bG[4];
  int ldsOff[4];
#pragma unroll
  for (int q = 0; q < 4; ++q) {
    const int row = wv * 32 + q * 8 + rS;
    const int lch = pS ^ (row & 7);
    aG[q] = (size_t)(b * O_ + oBase + row) * KDIM + lch * 8;
    const int hl = row >> 6, wl2 = row & 63;
    bG[q] = ((size_t)(b * XP_H + h0 + hl) * XP_H + wl2) * C_ + lch * 8;
    ldsOff[q] = (wv * 32 + q * 8) * 64;
  }

  // fragment geometry (mfma_f32_32x32x16_bf16):
  // A[m = lane&31][k = (lane>>5)*8 + j], B symmetric. wave-tile 64x64 = 2x2
  // frags of 32x32. phys slot de-swizzle: (ks*2 + half) ^ (row & 7).
  const int l31  = lane & 31;
  const int half = lane >> 5;
  const int mW = (wv & 1) << 6;
  const int nW = (wv >> 1) << 6;
  int aOff[4][2], bOff[4][2];
#pragma unroll
  for (int ks = 0; ks < 4; ++ks)
#pragma unroll
    for (int f = 0; f < 2; ++f) {
      const int ps = ((ks * 2 + half) ^ (l31 & 7)) * 8;    // shorts
      aOff[ks][f] = (mW + f * 32 + l31) * 64 + ps;
      bOff[ks][f] = (nW + f * 32 + l31) * 64 + ps;
    }

  floatx16 acc[2][2] = {};

  for (int tap = 0; tap < 9; ++tap) {
    const int toff = (tap / 3) * XP_H + (tap % 3);         // i*66 + j
#pragma unroll 1
    for (int c0 = 0; c0 < C_; c0 += 64) {
      const int kk = tap * C_ + c0;
      __syncthreads();
#pragma unroll
      for (int q = 0; q < 4; ++q) {
        gld_lds16(wagg + aG[q] + kk, lA + ldsOff[q]);
        gld_lds16(xpad + bG[q] + (size_t)toff * C_ + c0, lB + ldsOff[q]);
      }
      __builtin_amdgcn_s_waitcnt(0x0f70);                  // vmcnt(0)
      __syncthreads();

#pragma unroll
      for (int ks = 0; ks < 4; ++ks) {
        short8 af0 = *(const short8*)(lA + aOff[ks][0]);
        short8 af1 = *(const short8*)(lA + aOff[ks][1]);
        short8 bf0 = *(const short8*)(lB + bOff[ks][0]);
        short8 bf1 = *(const short8*)(lB + bOff[ks][1]);
        acc[0][0] = __builtin_amdgcn_mfma_f32_32x32x16_bf16(af0, bf0, acc[0][0], 0, 0, 0);
        acc[0][1] = __builtin_amdgcn_mfma_f32_32x32x16_bf16(af0, bf1, acc[0][1], 0, 0, 0);
        acc[1][0] = __builtin_amdgcn_mfma_f32_32x32x16_bf16(af1, bf0, acc[1][0], 0, 0, 0);
        acc[1][1] = __builtin_amdgcn_mfma_f32_32x32x16_bf16(af1, bf1, acc[1][1], 0, 0, 0);
      }
    }
  }

  // epilogue (32x32 C/D, m74/m101): col = lane&31,
  // row = (reg&3) + 8*(reg>>2) + 4*(lane>>5)
  const size_t outBase = (size_t)b * O_ * HW_;
#pragma unroll
  for (int mi = 0; mi < 2; ++mi) {
#pragma unroll
    for (int ni = 0; ni < 2; ++ni) {
      const int hw = hwBase + nW + ni * 32 + l31;
      const int o0 = oBase + mW + mi * 32 + 4 * half;
#pragma unroll
      for (int g = 0; g < 4; ++g)
#pragma unroll
        for (int r = 0; r < 4; ++r)
          out[outBase + (size_t)(o0 + g * 8 + r) * HW_ + hw] = acc[mi][ni][g * 4 + r];
    }
  }
}

// -------------------------------------------------------------- launch ------
extern "C" void kernel_launch(void* const* d_in, const int* in_sizes, int n_in,
                              void* d_out, int out_size, void* d_ws, size_t ws_size,
                              hipStream_t stream) {
  const float* x  = (const float*)d_in[0];   // [32,256,64,64]
  const float* w1 = (const float*)d_in[1];   // [65,256]
  const float* w2 = (const float*)d_in[2];   // [1024,65]
  const float* b2 = (const float*)d_in[3];   // [1024]
  const float* wt = (const float*)d_in[4];   // [4,256,256,3,3]
  float* out = (float*)d_out;                // [32,256,64,64]

  char* ws = (char*)d_ws;
  ushort_t* xpad = (ushort_t*)ws;                                  // 71.4 MB
  ushort_t* wagg = (ushort_t*)(ws + XPAD_ELEMS * 2);               // 37.7 MB
  float* partial = (float*)(ws + XPAD_ELEMS * 2 + WAGG_ELEMS * 2); // 2 MB
  float* attn    = partial + 64 * B_ * C_;                         // 128 KB

  border_kernel<<<dim3(B_, 4), 256, 0, stream>>>(xpad);
  pad_kernel<<<dim3(64, 4, B_), 256, 0, stream>>>(x, xpad, partial);
  attn_kernel<<<B_, 256, 0, stream>>>(partial, w1, w2, b2, attn);
  agg_kernel<<<dim3(O_, 4), 256, 0, stream>>>(attn, wt, wagg);
  gemm_kernel<<<dim3(32, 2, B_), 256, 0, stream>>>(xpad, wagg, out);
}